// Round 1
// baseline (3205.623 us; speedup 1.0000x reference)
//
#include <hip/hip_runtime.h>

// ---------------- types ----------------
typedef float f32x4 __attribute__((ext_vector_type(4)));
typedef __bf16 bf16x8 __attribute__((ext_vector_type(8)));
typedef unsigned short u16x4 __attribute__((ext_vector_type(4)));
typedef unsigned short u16x8 __attribute__((ext_vector_type(8)));

#define HIDDEN 4096
#define NH 32
#define NKV 2
#define HD 128
#define SLEN 2048
#define BATCH 2
#define QKV_OUT 4608  // NH*HD + 2*NKV*HD
#define MROWS 4096    // BATCH*SLEN
#define ATT_SCALE 0.08838834764831845f  // 128^-0.5

// fp32 -> bf16 (RNE) bit pattern
__device__ __forceinline__ unsigned short f2bf(float f) {
  unsigned int u = __float_as_uint(f);
  u += 0x7fffu + ((u >> 16) & 1u);
  return (unsigned short)(u >> 16);
}

__device__ __forceinline__ void gload16(const void* g, void* l) {
  __builtin_amdgcn_global_load_lds((const __attribute__((address_space(1))) void*)g,
                                   (__attribute__((address_space(3))) void*)l, 16, 0, 0);
}

// ---------------- fp32 -> bf16 convert ----------------
__global__ __launch_bounds__(256) void cvt_f32_bf16(const float* __restrict__ src,
                                                    unsigned short* __restrict__ dst,
                                                    int n4) {
  int stride = gridDim.x * blockDim.x;
  for (int i = blockIdx.x * blockDim.x + threadIdx.x; i < n4; i += stride) {
    float4 v = reinterpret_cast<const float4*>(src)[i];
    u16x4 o;
    o[0] = f2bf(v.x); o[1] = f2bf(v.y); o[2] = f2bf(v.z); o[3] = f2bf(v.w);
    reinterpret_cast<u16x4*>(dst)[i] = o;
  }
}

// ---------------- bf16 MFMA GEMM: C[M][N] = A[M][K] * B[N][K]^T (+bias) ----------------
// m97 structure: 128x128 tile, BK=32, 4 waves (2x2), 4x4 16x16x32 frags per wave,
// global_load_lds width-16 staging, linear LDS.
__global__ __launch_bounds__(256) void gemm_bf16_mfma(
    const unsigned short* __restrict__ A,  // bf16 bits [M][K]
    const unsigned short* __restrict__ B,  // bf16 bits [N][K]
    const float* __restrict__ bias,        // [N] or nullptr
    float* __restrict__ C,                 // fp32 [M][N]
    int M, int N, int K) {
  __shared__ unsigned short as_[128 * 32];
  __shared__ unsigned short bs_[128 * 32];
  const int tid = threadIdx.x;
  const int wave = tid >> 6;
  const int lane = tid & 63;
  const int m0 = blockIdx.y * 128;
  const int n0 = blockIdx.x * 128;
  const int wm = (wave >> 1) * 64;
  const int wn = (wave & 1) * 64;

  f32x4 acc[4][4] = {};

  // staging geometry: wave stages rows [wave*32, wave*32+32), 2 instrs of 1KB each
  const int srow = wave * 32 + (lane >> 2);
  const int scol = (lane & 3) * 8;  // bf16 elems (16B)
  unsigned short* lA = as_ + wave * 1024;
  unsigned short* lB = bs_ + wave * 1024;

  const int nk = K >> 5;
  for (int kt = 0; kt < nk; ++kt) {
    const int kb = kt << 5;
    __syncthreads();
    gload16(A + (size_t)(m0 + srow) * K + kb + scol, lA);
    gload16(A + (size_t)(m0 + srow + 16) * K + kb + scol, lA + 512);
    gload16(B + (size_t)(n0 + srow) * K + kb + scol, lB);
    gload16(B + (size_t)(n0 + srow + 16) * K + kb + scol, lB + 512);
    __syncthreads();

    bf16x8 aF[4], bF[4];
#pragma unroll
    for (int m4 = 0; m4 < 4; ++m4)
      aF[m4] = *reinterpret_cast<const bf16x8*>(
          &as_[(wm + m4 * 16 + (lane & 15)) * 32 + (lane >> 4) * 8]);
#pragma unroll
    for (int n4 = 0; n4 < 4; ++n4)
      bF[n4] = *reinterpret_cast<const bf16x8*>(
          &bs_[(wn + n4 * 16 + (lane & 15)) * 32 + (lane >> 4) * 8]);
#pragma unroll
    for (int m4 = 0; m4 < 4; ++m4)
#pragma unroll
      for (int n4 = 0; n4 < 4; ++n4)
        acc[m4][n4] =
            __builtin_amdgcn_mfma_f32_16x16x32_bf16(aF[m4], bF[n4], acc[m4][n4], 0, 0, 0);
  }

  // epilogue: C/D layout col=lane&15, row=(lane>>4)*4+reg
#pragma unroll
  for (int m4 = 0; m4 < 4; ++m4) {
#pragma unroll
    for (int n4 = 0; n4 < 4; ++n4) {
      const int col = n0 + wn + n4 * 16 + (lane & 15);
      const float bv = bias ? bias[col] : 0.0f;
#pragma unroll
      for (int r = 0; r < 4; ++r) {
        const int row = m0 + wm + m4 * 16 + (lane >> 4) * 4 + r;
        C[(size_t)row * N + col] = acc[m4][n4][r] + bv;
      }
    }
  }
}

// ---------------- GLM RoPE (interleaved pairs, first 64 of each 128-d head) ----------------
__global__ __launch_bounds__(256) void rope_kernel(float* __restrict__ mixed,
                                                   const int* __restrict__ positions) {
  const int m = blockIdx.x;
  const float pos = (float)positions[m];
  float* row = mixed + (size_t)m * QKV_OUT;
  for (int p = threadIdx.x; p < 34 * 32; p += 256) {  // 32 q heads + 2 k heads, 32 pairs
    const int hi = p >> 5;
    const int j = p & 31;
    const int base = (hi < 32) ? hi * 128 : 4096 + (hi - 32) * 128;
    const float inv = powf(10000.0f, -(float)j / 32.0f);
    float s, c;
    sincosf(pos * inv, &s, &c);
    const float x1 = row[base + 2 * j];
    const float x2 = row[base + 2 * j + 1];
    row[base + 2 * j] = x1 * c - x2 * s;
    row[base + 2 * j + 1] = x1 * s + x2 * c;
  }
}

// ---------------- fp32 flash attention (causal, GQA) ----------------
// 256 threads as 16x16 (ty,tx); 64 q-rows x 64 keys per tile; thread owns 4x4 scores
// and 4 rows x 8 d-cols of O. q/k stored transposed [d][row] in LDS (conflict-free QK reads).
__global__ __launch_bounds__(256) void flash_attn(const float* __restrict__ mixed,
                                                  unsigned short* __restrict__ ctx) {
  __shared__ float q_s[128 * 64];
  __shared__ float k_s[128 * 64];
  __shared__ float v_s[64 * 132];
  __shared__ float p_s[64 * 65];

  const int tid = threadIdx.x;
  const int ty = tid >> 4, tx = tid & 15;
  const int qt = blockIdx.x, h = blockIdx.y, b = blockIdx.z;
  const int kv = h >> 4;  // G = 16
  const int q0 = qt * 64;

  // stage q transposed
  const float* qg = mixed + (size_t)(b * SLEN + q0) * QKV_OUT + h * HD;
#pragma unroll
  for (int i = 0; i < 8; ++i) {
    const int f = tid * 8 + i;
    const int r = f >> 5, dq = f & 31;
    float4 v = *reinterpret_cast<const float4*>(qg + (size_t)r * QKV_OUT + dq * 4);
    q_s[(dq * 4 + 0) * 64 + r] = v.x;
    q_s[(dq * 4 + 1) * 64 + r] = v.y;
    q_s[(dq * 4 + 2) * 64 + r] = v.z;
    q_s[(dq * 4 + 3) * 64 + r] = v.w;
  }

  f32x4 acc[4][2] = {};
  float mi[4], li[4];
#pragma unroll
  for (int i = 0; i < 4; ++i) { mi[i] = -1e30f; li[i] = 0.0f; }

  for (int kt = 0; kt <= qt; ++kt) {
    const int s0 = kt * 64;
    const float* kg = mixed + (size_t)(b * SLEN + s0) * QKV_OUT + NH * HD + kv * HD;
    const float* vg = kg + NKV * HD;  // v block follows k block
    __syncthreads();  // prev iteration's k_s/v_s/p_s consumers done
    // stage k transposed
#pragma unroll
    for (int i = 0; i < 8; ++i) {
      const int f = tid * 8 + i;
      const int r = f >> 5, dq = f & 31;
      float4 v = *reinterpret_cast<const float4*>(kg + (size_t)r * QKV_OUT + dq * 4);
      k_s[(dq * 4 + 0) * 64 + r] = v.x;
      k_s[(dq * 4 + 1) * 64 + r] = v.y;
      k_s[(dq * 4 + 2) * 64 + r] = v.z;
      k_s[(dq * 4 + 3) * 64 + r] = v.w;
    }
    // stage v natural [64][132]
#pragma unroll
    for (int i = 0; i < 8; ++i) {
      const int f = (i << 8) + tid;
      const int r = f >> 5, dq = f & 31;
      *reinterpret_cast<float4*>(&v_s[r * 132 + dq * 4]) =
          *reinterpret_cast<const float4*>(vg + (size_t)r * QKV_OUT + dq * 4);
    }
    __syncthreads();

    // QK^T
    float sc[4][4] = {};
#pragma unroll 4
    for (int d = 0; d < 128; ++d) {
      f32x4 q4 = *reinterpret_cast<const f32x4*>(&q_s[d * 64 + ty * 4]);
      f32x4 k4 = *reinterpret_cast<const f32x4*>(&k_s[d * 64 + tx * 4]);
#pragma unroll
      for (int i = 0; i < 4; ++i)
#pragma unroll
        for (int j = 0; j < 4; ++j) sc[i][j] += q4[i] * k4[j];
    }

    // scale + causal mask + online softmax (row groups = 16 lanes sharing ty)
#pragma unroll
    for (int i = 0; i < 4; ++i) {
      const int qrow = q0 + ty * 4 + i;
      float rm = -1e30f;
#pragma unroll
      for (int j = 0; j < 4; ++j) {
        float v = sc[i][j] * ATT_SCALE;
        if (s0 + tx * 4 + j > qrow) v = -1e30f;
        sc[i][j] = v;
        rm = fmaxf(rm, v);
      }
      rm = fmaxf(rm, __shfl_xor(rm, 1));
      rm = fmaxf(rm, __shfl_xor(rm, 2));
      rm = fmaxf(rm, __shfl_xor(rm, 4));
      rm = fmaxf(rm, __shfl_xor(rm, 8));
      const float mnew = fmaxf(mi[i], rm);
      const float cf = __expf(mi[i] - mnew);
      float rs = 0.0f;
#pragma unroll
      for (int j = 0; j < 4; ++j) {
        const float p = __expf(sc[i][j] - mnew);
        sc[i][j] = p;
        rs += p;
      }
      rs += __shfl_xor(rs, 1);
      rs += __shfl_xor(rs, 2);
      rs += __shfl_xor(rs, 4);
      rs += __shfl_xor(rs, 8);
      li[i] = li[i] * cf + rs;
      mi[i] = mnew;
      acc[i][0] *= cf;
      acc[i][1] *= cf;
    }

    // publish P (prev PV readers already synced at loop top)
#pragma unroll
    for (int i = 0; i < 4; ++i)
#pragma unroll
      for (int j = 0; j < 4; ++j) p_s[(ty * 4 + i) * 65 + tx * 4 + j] = sc[i][j];
    __syncthreads();

    // PV accumulate: O[r][tx*8..+8]
#pragma unroll 2
    for (int j = 0; j < 64; ++j) {
      f32x4 va = *reinterpret_cast<const f32x4*>(&v_s[j * 132 + tx * 8]);
      f32x4 vb = *reinterpret_cast<const f32x4*>(&v_s[j * 132 + tx * 8 + 4]);
#pragma unroll
      for (int i = 0; i < 4; ++i) {
        const float pj = p_s[(ty * 4 + i) * 65 + j];
        acc[i][0] += pj * va;
        acc[i][1] += pj * vb;
      }
    }
  }

  // write ctx as bf16 bits
#pragma unroll
  for (int i = 0; i < 4; ++i) {
    const float inv = 1.0f / li[i];
    u16x8 o;
#pragma unroll
    for (int jj = 0; jj < 4; ++jj) o[jj] = f2bf(acc[i][0][jj] * inv);
#pragma unroll
    for (int jj = 0; jj < 4; ++jj) o[4 + jj] = f2bf(acc[i][1][jj] * inv);
    const size_t orow =
        (size_t)(b * SLEN + q0 + ty * 4 + i) * (size_t)HIDDEN + h * HD + tx * 8;
    *reinterpret_cast<u16x8*>(&ctx[orow]) = o;
  }
}

// ---------------- launch ----------------
extern "C" void kernel_launch(void* const* d_in, const int* in_sizes, int n_in,
                              void* d_out, int out_size, void* d_ws, size_t ws_size,
                              hipStream_t stream) {
  const int* positions = (const int*)d_in[0];
  const float* hidden = (const float*)d_in[1];
  const float* w_qkv = (const float*)d_in[2];
  const float* b_qkv = (const float*)d_in[3];
  const float* w_dense = (const float*)d_in[4];
  float* out = (float*)d_out;

  char* ws = (char*)d_ws;
  size_t off = 0;
  float* mixed = (float*)(ws + off);
  off += (size_t)MROWS * QKV_OUT * 4;  // 75.5 MB
  unsigned short* h_bf = (unsigned short*)(ws + off);
  off += (size_t)MROWS * HIDDEN * 2;  // 33.6 MB
  unsigned short* wq_bf = (unsigned short*)(ws + off);
  off += (size_t)QKV_OUT * HIDDEN * 2;  // 37.7 MB
  unsigned short* wd_bf = (unsigned short*)(ws + off);
  off += (size_t)HIDDEN * HIDDEN * 2;  // 33.6 MB
  unsigned short* ctx_bf = (unsigned short*)(ws + off);
  off += (size_t)MROWS * HIDDEN * 2;  // 33.6 MB  (total ~214 MB)

  cvt_f32_bf16<<<2048, 256, 0, stream>>>(hidden, h_bf, MROWS * HIDDEN / 4);
  cvt_f32_bf16<<<2048, 256, 0, stream>>>(w_qkv, wq_bf, QKV_OUT * HIDDEN / 4);
  cvt_f32_bf16<<<2048, 256, 0, stream>>>(w_dense, wd_bf, HIDDEN * HIDDEN / 4);

  gemm_bf16_mfma<<<dim3(QKV_OUT / 128, MROWS / 128), 256, 0, stream>>>(
      h_bf, wq_bf, b_qkv, mixed, MROWS, QKV_OUT, HIDDEN);

  rope_kernel<<<MROWS, 256, 0, stream>>>(mixed, positions);

  flash_attn<<<dim3(SLEN / 64, NH, BATCH), 256, 0, stream>>>(mixed, ctx_bf);

  gemm_bf16_mfma<<<dim3(HIDDEN / 128, MROWS / 128), 256, 0, stream>>>(
      ctx_bf, wd_bf, nullptr, out, MROWS, HIDDEN, HIDDEN);
}

// Round 2
// 829.610 us; speedup vs baseline: 3.8640x; 3.8640x over previous
//
#include <hip/hip_runtime.h>

// ---------------- types ----------------
typedef float f32x4 __attribute__((ext_vector_type(4)));
typedef __bf16 bf16x8 __attribute__((ext_vector_type(8)));
typedef unsigned short u16x4 __attribute__((ext_vector_type(4)));
typedef unsigned short u16x8 __attribute__((ext_vector_type(8)));

#define HIDDEN 4096
#define NH 32
#define NKV 2
#define HD 128
#define SLEN 2048
#define BATCH 2
#define QKV_OUT 4608  // NH*HD + 2*NKV*HD
#define MROWS 4096    // BATCH*SLEN
#define ATT_SCALE 0.08838834764831845f  // 128^-0.5

// fp32 -> bf16 (RNE) bit pattern
__device__ __forceinline__ unsigned short f2bf(float f) {
  unsigned int u = __float_as_uint(f);
  u += 0x7fffu + ((u >> 16) & 1u);
  return (unsigned short)(u >> 16);
}

__device__ __forceinline__ void gload16(const void* g, void* l) {
  __builtin_amdgcn_global_load_lds((const __attribute__((address_space(1))) void*)g,
                                   (__attribute__((address_space(3))) void*)l, 16, 0, 0);
}

// ---------------- fp32 -> bf16 convert ----------------
__global__ __launch_bounds__(256) void cvt_f32_bf16(const float* __restrict__ src,
                                                    unsigned short* __restrict__ dst,
                                                    int n4) {
  int stride = gridDim.x * blockDim.x;
  for (int i = blockIdx.x * blockDim.x + threadIdx.x; i < n4; i += stride) {
    float4 v = reinterpret_cast<const float4*>(src)[i];
    u16x4 o;
    o[0] = f2bf(v.x); o[1] = f2bf(v.y); o[2] = f2bf(v.z); o[3] = f2bf(v.w);
    reinterpret_cast<u16x4*>(dst)[i] = o;
  }
}

// ---------------- bf16 MFMA GEMM: C[M][N] = A[M][K] * B[N][K]^T (+bias) ----------------
__global__ __launch_bounds__(256) void gemm_bf16_mfma(
    const unsigned short* __restrict__ A,  // bf16 bits [M][K]
    const unsigned short* __restrict__ B,  // bf16 bits [N][K]
    const float* __restrict__ bias,        // [N] or nullptr
    float* __restrict__ C,                 // fp32 [M][N]
    int M, int N, int K) {
  __shared__ unsigned short as_[128 * 32];
  __shared__ unsigned short bs_[128 * 32];
  const int tid = threadIdx.x;
  const int wave = tid >> 6;
  const int lane = tid & 63;
  const int m0 = blockIdx.y * 128;
  const int n0 = blockIdx.x * 128;
  const int wm = (wave >> 1) * 64;
  const int wn = (wave & 1) * 64;

  f32x4 acc[4][4] = {};

  const int srow = wave * 32 + (lane >> 2);
  const int scol = (lane & 3) * 8;
  unsigned short* lA = as_ + wave * 1024;
  unsigned short* lB = bs_ + wave * 1024;

  const int nk = K >> 5;
  for (int kt = 0; kt < nk; ++kt) {
    const int kb = kt << 5;
    __syncthreads();
    gload16(A + (size_t)(m0 + srow) * K + kb + scol, lA);
    gload16(A + (size_t)(m0 + srow + 16) * K + kb + scol, lA + 512);
    gload16(B + (size_t)(n0 + srow) * K + kb + scol, lB);
    gload16(B + (size_t)(n0 + srow + 16) * K + kb + scol, lB + 512);
    __syncthreads();

    bf16x8 aF[4], bF[4];
#pragma unroll
    for (int m4 = 0; m4 < 4; ++m4)
      aF[m4] = *reinterpret_cast<const bf16x8*>(
          &as_[(wm + m4 * 16 + (lane & 15)) * 32 + (lane >> 4) * 8]);
#pragma unroll
    for (int n4 = 0; n4 < 4; ++n4)
      bF[n4] = *reinterpret_cast<const bf16x8*>(
          &bs_[(wn + n4 * 16 + (lane & 15)) * 32 + (lane >> 4) * 8]);
#pragma unroll
    for (int m4 = 0; m4 < 4; ++m4)
#pragma unroll
      for (int n4 = 0; n4 < 4; ++n4)
        acc[m4][n4] =
            __builtin_amdgcn_mfma_f32_16x16x32_bf16(aF[m4], bF[n4], acc[m4][n4], 0, 0, 0);
  }

#pragma unroll
  for (int m4 = 0; m4 < 4; ++m4) {
#pragma unroll
    for (int n4 = 0; n4 < 4; ++n4) {
      const int col = n0 + wn + n4 * 16 + (lane & 15);
      const float bv = bias ? bias[col] : 0.0f;
#pragma unroll
      for (int r = 0; r < 4; ++r) {
        const int row = m0 + wm + m4 * 16 + (lane >> 4) * 4 + r;
        C[(size_t)row * N + col] = acc[m4][n4][r] + bv;
      }
    }
  }
}

// ---------------- prep: RoPE (fp32) + bf16 + head-major layouts ----------------
// Qb [B][NH][S][HD], Kb [B][NKV][S][HD], Vt [B][NKV][HD][S]  (V transposed)
__global__ __launch_bounds__(256) void prep_qkv(const float* __restrict__ mixed,
                                                const int* __restrict__ positions,
                                                unsigned short* __restrict__ Qb,
                                                unsigned short* __restrict__ Kb,
                                                unsigned short* __restrict__ Vt) {
  const int m = blockIdx.x;
  const int b = m >> 11, s = m & 2047;
  const float pos = (float)positions[m];
  const float2* row = reinterpret_cast<const float2*>(mixed + (size_t)m * QKV_OUT);
#pragma unroll
  for (int it = 0; it < 9; ++it) {
    const int p = it * 256 + threadIdx.x;  // pair index, 2304 total
    const int col = p * 2;
    float2 x = row[p];
    float r1 = x.x, r2 = x.y;
    const int d = col & 127;
    const bool is_v = (col >= NH * HD + NKV * HD);
    if (d < 64 && !is_v) {
      const int j = d >> 1;
      const float inv = powf(10000.0f, -(float)j * (1.0f / 32.0f));
      float sn, cs;
      sincosf(pos * inv, &sn, &cs);
      r1 = x.x * cs - x.y * sn;
      r2 = x.x * sn + x.y * cs;
    }
    const unsigned int packed = (unsigned int)f2bf(r1) | ((unsigned int)f2bf(r2) << 16);
    if (col < NH * HD) {
      const int h = col >> 7;
      *reinterpret_cast<unsigned int*>(
          &Qb[((size_t)(b * NH + h) * SLEN + s) * HD + d]) = packed;
    } else if (!is_v) {
      const int kv = (col - NH * HD) >> 7;
      *reinterpret_cast<unsigned int*>(
          &Kb[((size_t)(b * NKV + kv) * SLEN + s) * HD + d]) = packed;
    } else {
      const int kv = (col - NH * HD - NKV * HD) >> 7;
      unsigned short* vb = Vt + ((size_t)(b * NKV + kv) * HD) * SLEN + s;
      vb[(size_t)d * SLEN] = f2bf(r1);
      vb[(size_t)(d + 1) * SLEN] = f2bf(r2);
    }
  }
}

// ---------------- bf16 MFMA flash attention (causal, GQA) ----------------
// 4 waves; wave owns 16 q-rows. KVBLK=64. All LDS tiles XOR-swizzled (T2/G4);
// K and V^T staged via global_load_lds with pre-swizzled global source (rule #21).
__global__ __launch_bounds__(256) void flash_mfma(const unsigned short* __restrict__ Qb,
                                                  const unsigned short* __restrict__ Kb,
                                                  const unsigned short* __restrict__ Vt,
                                                  unsigned short* __restrict__ ctx) {
  __shared__ unsigned short Ks[64 * 128];   // [key][d] swizzled, 16 KB
  __shared__ unsigned short Vs[128 * 64];   // [d][key] swizzled, 16 KB
  __shared__ unsigned short Ps[4 * 16 * 64];  // per-wave P [q][key] swizzled, 8 KB

  const int tid = threadIdx.x;
  const int wave = tid >> 6, lane = tid & 63;
  const int lr = lane & 15, lg = lane >> 4;
  const int qt = 31 - blockIdx.x;  // heavy tiles first
  const int h = blockIdx.y, b = blockIdx.z;
  const int kv = h >> 4;  // G = 16
  const int q0 = qt * 64;

  // Q fragments: A operand, row = lr, k = lg*8 + ks*32
  const unsigned short* qrow = Qb + ((size_t)(b * NH + h) * SLEN + q0 + wave * 16 + lr) * HD;
  bf16x8 aQ[4];
#pragma unroll
  for (int ks = 0; ks < 4; ++ks)
    aQ[ks] = *reinterpret_cast<const bf16x8*>(qrow + lg * 8 + ks * 32);

  const unsigned short* Kbase = Kb + (size_t)(b * NKV + kv) * SLEN * HD;
  const unsigned short* Vbase = Vt + (size_t)(b * NKV + kv) * HD * SLEN;

  f32x4 accO[8] = {};
  float mi[4], li[4];
#pragma unroll
  for (int r = 0; r < 4; ++r) { mi[r] = -1e30f; li[r] = 0.0f; }

  for (int kt = 0; kt <= qt; ++kt) {
    const int s0 = kt * 64;
    __syncthreads();
    // stage K [64][128] and V^T [128][64], swizzled via global source address
#pragma unroll
    for (int i = 0; i < 4; ++i) {
      const int krow = wave * 16 + i * 4 + lg;
      gload16(Kbase + (size_t)(s0 + krow) * HD + ((lr ^ (krow & 7)) << 3),
              Ks + (wave * 16 + i * 4) * 128);
      const int drow = wave * 32 + i * 8 + (lane >> 3);
      gload16(Vbase + (size_t)drow * SLEN + s0 + (((lane & 7) ^ (drow & 7)) << 3),
              Vs + (wave * 32 + i * 8) * 64);
    }
    __syncthreads();

    // ---- S = Q K^T ----
    f32x4 accS[4] = {};
#pragma unroll
    for (int n4 = 0; n4 < 4; ++n4) {
      const int krow = n4 * 16 + lr;
      const unsigned short* kl = Ks + krow * 128;
#pragma unroll
      for (int ks = 0; ks < 4; ++ks) {
        bf16x8 bK = *reinterpret_cast<const bf16x8*>(kl + (((ks * 4 + lg) ^ (krow & 7)) << 3));
        accS[n4] = __builtin_amdgcn_mfma_f32_16x16x32_bf16(aQ[ks], bK, accS[n4], 0, 0, 0);
      }
    }

    // ---- online softmax; P -> swizzled per-wave LDS ----
    const bool diag = (kt == qt);
#pragma unroll
    for (int r = 0; r < 4; ++r) {
      const int qloc = lg * 4 + r;  // q-row within wave's 16
      float v[4];
#pragma unroll
      for (int n4 = 0; n4 < 4; ++n4) {
        float sv = accS[n4][r] * ATT_SCALE;
        if (diag && (n4 * 16 + lr > wave * 16 + qloc)) sv = -1e30f;
        v[n4] = sv;
      }
      float rm = fmaxf(fmaxf(v[0], v[1]), fmaxf(v[2], v[3]));
      rm = fmaxf(rm, __shfl_xor(rm, 1));
      rm = fmaxf(rm, __shfl_xor(rm, 2));
      rm = fmaxf(rm, __shfl_xor(rm, 4));
      rm = fmaxf(rm, __shfl_xor(rm, 8));
      const float mnew = fmaxf(mi[r], rm);
      const float cf = __expf(mi[r] - mnew);
      mi[r] = mnew;
      float rs = 0.0f;
#pragma unroll
      for (int n4 = 0; n4 < 4; ++n4) {
        const float pv = __expf(v[n4] - mnew);
        v[n4] = pv;
        rs += pv;
      }
      rs += __shfl_xor(rs, 1);
      rs += __shfl_xor(rs, 2);
      rs += __shfl_xor(rs, 4);
      rs += __shfl_xor(rs, 8);
      li[r] = li[r] * cf + rs;
#pragma unroll
      for (int n8 = 0; n8 < 8; ++n8) accO[n8][r] *= cf;
      // write P[qloc][key=n4*16+lr] swizzled: slot = key>>3 xor (qloc&7), byte = key&7
#pragma unroll
      for (int n4 = 0; n4 < 4; ++n4) {
        const int slot = (n4 * 2 + (lr >> 3)) ^ (qloc & 7);
        Ps[wave * 1024 + qloc * 64 + (slot << 3) + (lr & 7)] = f2bf(v[n4]);
      }
    }

    // ---- O += P V ----
#pragma unroll
    for (int ks = 0; ks < 2; ++ks) {
      bf16x8 pa = *reinterpret_cast<const bf16x8*>(
          Ps + wave * 1024 + lr * 64 + ((((ks * 4) + lg) ^ (lr & 7)) << 3));
#pragma unroll
      for (int n8 = 0; n8 < 8; ++n8) {
        const int drow = n8 * 16 + lr;
        bf16x8 bV = *reinterpret_cast<const bf16x8*>(
            Vs + drow * 64 + ((((ks * 4) + lg) ^ (drow & 7)) << 3));
        accO[n8] = __builtin_amdgcn_mfma_f32_16x16x32_bf16(pa, bV, accO[n8], 0, 0, 0);
      }
    }
  }

  // epilogue: ctx[b*S + q][h*128 + d] bf16
#pragma unroll
  for (int r = 0; r < 4; ++r) {
    const float inv = 1.0f / li[r];
    unsigned short* orow =
        ctx + (size_t)(b * SLEN + q0 + wave * 16 + lg * 4 + r) * HIDDEN + h * HD;
#pragma unroll
    for (int n8 = 0; n8 < 8; ++n8) orow[n8 * 16 + lr] = f2bf(accO[n8][r] * inv);
  }
}

// ---------------- launch ----------------
extern "C" void kernel_launch(void* const* d_in, const int* in_sizes, int n_in,
                              void* d_out, int out_size, void* d_ws, size_t ws_size,
                              hipStream_t stream) {
  const int* positions = (const int*)d_in[0];
  const float* hidden = (const float*)d_in[1];
  const float* w_qkv = (const float*)d_in[2];
  const float* b_qkv = (const float*)d_in[3];
  const float* w_dense = (const float*)d_in[4];
  float* out = (float*)d_out;

  char* ws = (char*)d_ws;
  size_t off = 0;
  float* mixed = (float*)(ws + off);
  off += (size_t)MROWS * QKV_OUT * 4;  // 75.5 MB
  unsigned short* h_bf = (unsigned short*)(ws + off);
  off += (size_t)MROWS * HIDDEN * 2;  // 33.6 MB (reused as Qb after QKV GEMM)
  unsigned short* wq_bf = (unsigned short*)(ws + off);
  off += (size_t)QKV_OUT * HIDDEN * 2;  // 37.7 MB
  unsigned short* wd_bf = (unsigned short*)(ws + off);
  off += (size_t)HIDDEN * HIDDEN * 2;  // 33.6 MB
  unsigned short* Kb = (unsigned short*)(ws + off);
  off += (size_t)BATCH * NKV * SLEN * HD * 2;  // 2 MB
  unsigned short* Vt = (unsigned short*)(ws + off);
  off += (size_t)BATCH * NKV * SLEN * HD * 2;  // 2 MB
  unsigned short* Qb = h_bf;               // alias: h_bf dead after QKV GEMM
  unsigned short* ctx_bf = (unsigned short*)mixed;  // alias: mixed dead after prep

  cvt_f32_bf16<<<2048, 256, 0, stream>>>(hidden, h_bf, MROWS * HIDDEN / 4);
  cvt_f32_bf16<<<2048, 256, 0, stream>>>(w_qkv, wq_bf, QKV_OUT * HIDDEN / 4);
  cvt_f32_bf16<<<2048, 256, 0, stream>>>(w_dense, wd_bf, HIDDEN * HIDDEN / 4);

  gemm_bf16_mfma<<<dim3(QKV_OUT / 128, MROWS / 128), 256, 0, stream>>>(
      h_bf, wq_bf, b_qkv, mixed, MROWS, QKV_OUT, HIDDEN);

  prep_qkv<<<MROWS, 256, 0, stream>>>(mixed, positions, Qb, Kb, Vt);

  flash_mfma<<<dim3(SLEN / 64, NH, BATCH), 256, 0, stream>>>(Qb, Kb, Vt, ctx_bf);

  gemm_bf16_mfma<<<dim3(HIDDEN / 128, MROWS / 128), 256, 0, stream>>>(
      ctx_bf, wd_bf, nullptr, out, MROWS, HIDDEN, HIDDEN);
}